// Round 1
// baseline (8340.977 us; speedup 1.0000x reference)
//
#include <hip/hip_runtime.h>
#include <hip/hip_bf16.h>
#include <math.h>

// Problem constants (Qwen3-style attention block)
#define B_   2
#define S_   2048
#define D_   2048
#define H_   16
#define HK_  8
#define HD_  128
#define BS_  (B_ * S_)          // 4096 rows
#define SCALE 0.08838834764831845f  // 1/sqrt(128)

// ---------------------------------------------------------------------------
// NT GEMM: C[M,N] = A[M,K] * W[N,K]^T   (both A and W are K-contiguous)
// 64x64 tile, BK=16, 256 threads, 4x4 micro-tile per thread. fp32.
// ---------------------------------------------------------------------------
__global__ __launch_bounds__(256) void gemm_nt(const float* __restrict__ A,
                                               const float* __restrict__ W,
                                               float* __restrict__ C,
                                               int M, int N, int K) {
    __shared__ float As[64][17];
    __shared__ float Ws[64][17];

    const int t  = threadIdx.x;
    const int tx = t & 15;        // 0..15 -> N direction
    const int ty = t >> 4;        // 0..15 -> M direction
    const int m0 = blockIdx.y * 64;
    const int n0 = blockIdx.x * 64;

    const int lr = t >> 2;        // 0..63 (tile row for loading)
    const int lc = (t & 3) * 4;   // 0,4,8,12 (k-col for loading, float4)

    float acc[4][4] = {};

    for (int k0 = 0; k0 < K; k0 += 16) {
        float4 av = *reinterpret_cast<const float4*>(&A[(size_t)(m0 + lr) * K + k0 + lc]);
        float4 wv = *reinterpret_cast<const float4*>(&W[(size_t)(n0 + lr) * K + k0 + lc]);
        As[lr][lc + 0] = av.x; As[lr][lc + 1] = av.y;
        As[lr][lc + 2] = av.z; As[lr][lc + 3] = av.w;
        Ws[lr][lc + 0] = wv.x; Ws[lr][lc + 1] = wv.y;
        Ws[lr][lc + 2] = wv.z; Ws[lr][lc + 3] = wv.w;
        __syncthreads();

        #pragma unroll
        for (int kk = 0; kk < 16; kk++) {
            float a[4], w[4];
            #pragma unroll
            for (int i = 0; i < 4; i++) a[i] = As[ty * 4 + i][kk];
            #pragma unroll
            for (int j = 0; j < 4; j++) w[j] = Ws[tx * 4 + j][kk];
            #pragma unroll
            for (int i = 0; i < 4; i++)
                #pragma unroll
                for (int j = 0; j < 4; j++)
                    acc[i][j] = fmaf(a[i], w[j], acc[i][j]);
        }
        __syncthreads();
    }

    #pragma unroll
    for (int i = 0; i < 4; i++) {
        #pragma unroll
        for (int j = 0; j < 4; j++) {
            C[(size_t)(m0 + ty * 4 + i) * N + n0 + tx * 4 + j] = acc[i][j];
        }
    }
}

// ---------------------------------------------------------------------------
// Fused per-head RMSNorm + RoPE (in-place on the projected q or k buffer).
// One 128-thread block per (b*s, head). buf layout: [BS, nheads*HD].
// ---------------------------------------------------------------------------
__global__ __launch_bounds__(128) void norm_rope(float* __restrict__ buf,
                                                 const float* __restrict__ w,
                                                 int nheads) {
    __shared__ float sred[2];
    __shared__ float nv[128];

    const int row  = blockIdx.x;          // b*S + s
    const int s    = row & (S_ - 1);      // position
    const int head = blockIdx.y;
    const int d    = threadIdx.x;

    float* p = buf + (size_t)row * nheads * HD_ + (size_t)head * HD_;
    float x = p[d];

    // sum of squares over 128 elems (2 waves)
    float ss = x * x;
    #pragma unroll
    for (int off = 32; off; off >>= 1) ss += __shfl_xor(ss, off);
    if ((threadIdx.x & 63) == 0) sred[threadIdx.x >> 6] = ss;
    __syncthreads();
    float mean = (sred[0] + sred[1]) * (1.0f / 128.0f);
    float rs = rsqrtf(mean + 1e-6f);

    float n = x * rs * w[d];
    nv[d] = n;
    __syncthreads();

    const int i = d & 63;
    // inv_freq = THETA^(-2i/128) ; log(1e6) = 13.815510557964274
    float inv_freq = expf(-13.815510557964274f * (float)(2 * i) * (1.0f / 128.0f));
    float ang = (float)s * inv_freq;
    float sn, cs;
    sincosf(ang, &sn, &cs);

    float other = nv[d ^ 64];
    float r = (d < 64) ? (n * cs - other * sn)   // x1*c - x2*s
                       : (other * sn + n * cs);  // x1*s + x2*c
    p[d] = r;
}

// ---------------------------------------------------------------------------
// Causal GQA flash attention (online softmax).
// Grid: (S/4, B*H). Block: 256 threads = 4 waves; wave w handles q-row
// blockIdx.x*4+w of head blockIdx.y. K tile staged with rotation swizzle
// (conflict-free lane-per-key reads); V tile unswizzled (lane indexes d).
// LDS = exactly 64 KiB.
// ---------------------------------------------------------------------------
__global__ __launch_bounds__(256) void attn_fwd(const float* __restrict__ Q,
                                                const float* __restrict__ Kg,
                                                const float* __restrict__ Vg,
                                                float* __restrict__ O) {
    __shared__ float Kt[64 * 128];
    __shared__ float Vt[64 * 128];

    const int w    = threadIdx.x >> 6;
    const int lane = threadIdx.x & 63;
    const int bh   = blockIdx.y;
    const int b    = bh >> 4;           // / H_
    const int h    = bh & 15;           // % H_
    const int kvh  = h >> 1;            // GQA: rep = H/HK = 2
    const int qmax = blockIdx.x * 4 + 3;
    const int qrow = blockIdx.x * 4 + w;

    const size_t qoff = ((size_t)((b * S_ + qrow) * H_) + h) * HD_;
    const float q0 = Q[qoff + lane];
    const float q1 = Q[qoff + 64 + lane];

    float m = -INFINITY, l = 0.0f, acc0 = 0.0f, acc1 = 0.0f;

    for (int t0 = 0; t0 <= qmax; t0 += 64) {
        // ---- stage K (swizzled) and V (plain) tiles: 64 keys x 128 dims ----
        #pragma unroll 4
        for (int i = 0; i < 32; i++) {
            int flat = threadIdx.x + i * 256;
            int r = flat >> 7;
            int c = flat & 127;
            size_t g = ((size_t)((b * S_ + t0 + r) * HK_) + kvh) * HD_;
            Kt[r * 128 + ((c + r) & 127)] = Kg[g + c];
            Vt[r * 128 + c]               = Vg[g + c];
        }
        __syncthreads();

        // ---- scores: lane j handles key t0+j ----
        float sc = 0.0f;
        const int kbase = lane * 128;
        #pragma unroll 8
        for (int d = 0; d < 64; d++) {
            float qa = __shfl(q0, d);
            float qb = __shfl(q1, d);
            sc = fmaf(qa, Kt[kbase + ((d + lane) & 127)], sc);
            sc = fmaf(qb, Kt[kbase + ((d + 64 + lane) & 127)], sc);
        }
        sc *= SCALE;
        const int key = t0 + lane;
        const bool valid = (key <= qrow);
        if (!valid) sc = -INFINITY;

        // tile max
        float mt = sc;
        #pragma unroll
        for (int off = 32; off; off >>= 1) mt = fmaxf(mt, __shfl_xor(mt, off));
        float mnew = fmaxf(m, mt);
        float alpha = __expf(m - mnew);
        float p = valid ? __expf(sc - mnew) : 0.0f;

        float ts = p;
        #pragma unroll
        for (int off = 32; off; off >>= 1) ts += __shfl_xor(ts, off);

        l = l * alpha + ts;
        acc0 *= alpha;
        acc1 *= alpha;

        const int jmax = min(63, qrow - t0);
        for (int j = 0; j <= jmax; j++) {
            float pj = __shfl(p, j);
            acc0 = fmaf(pj, Vt[j * 128 + lane], acc0);
            acc1 = fmaf(pj, Vt[j * 128 + 64 + lane], acc1);
        }
        m = mnew;
        __syncthreads();
    }

    float inv_l = 1.0f / l;
    O[qoff + lane]      = acc0 * inv_l;
    O[qoff + 64 + lane] = acc1 * inv_l;
}

// ---------------------------------------------------------------------------
extern "C" void kernel_launch(void* const* d_in, const int* in_sizes, int n_in,
                              void* d_out, int out_size, void* d_ws, size_t ws_size,
                              hipStream_t stream) {
    const float* x  = (const float*)d_in[0];
    const float* wq = (const float*)d_in[1];
    const float* wk = (const float*)d_in[2];
    const float* wv = (const float*)d_in[3];
    const float* wo = (const float*)d_in[4];
    const float* qw = (const float*)d_in[5];
    const float* kw = (const float*)d_in[6];
    float* out = (float*)d_out;

    float* ws   = (float*)d_ws;
    float* q    = ws;                                  // BS * H*HD  = 8388608
    float* kbuf = q    + (size_t)BS_ * H_  * HD_;      // BS * HK*HD = 4194304
    float* vbuf = kbuf + (size_t)BS_ * HK_ * HD_;      // BS * HK*HD = 4194304
    float* ao   = vbuf + (size_t)BS_ * HK_ * HD_;      // BS * H*HD  = 8388608
    // total: 25165824 floats = ~101 MB of d_ws

    // QKV projections
    gemm_nt<<<dim3((H_ * HD_) / 64, BS_ / 64), 256, 0, stream>>>(x, wq, q,    BS_, H_ * HD_,  D_);
    gemm_nt<<<dim3((HK_ * HD_) / 64, BS_ / 64), 256, 0, stream>>>(x, wk, kbuf, BS_, HK_ * HD_, D_);
    gemm_nt<<<dim3((HK_ * HD_) / 64, BS_ / 64), 256, 0, stream>>>(x, wv, vbuf, BS_, HK_ * HD_, D_);

    // RMSNorm + RoPE on q and k
    norm_rope<<<dim3(BS_, H_),  128, 0, stream>>>(q,    qw, H_);
    norm_rope<<<dim3(BS_, HK_), 128, 0, stream>>>(kbuf, kw, HK_);

    // Causal GQA attention
    attn_fwd<<<dim3(S_ / 4, B_ * H_), 256, 0, stream>>>(q, kbuf, vbuf, ao);

    // Output projection
    gemm_nt<<<dim3(D_ / 64, BS_ / 64), 256, 0, stream>>>(ao, wo, out, BS_, D_, H_ * HD_);
}

// Round 2
// 2616.226 us; speedup vs baseline: 3.1882x; 3.1882x over previous
//
#include <hip/hip_runtime.h>
#include <hip/hip_bf16.h>
#include <math.h>

// Problem constants (Qwen3-style attention block)
#define B_   2
#define S_   2048
#define D_   2048
#define H_   16
#define HK_  8
#define HD_  128
#define BS_  (B_ * S_)          // 4096 rows
#define SCALE 0.08838834764831845f  // 1/sqrt(128)

typedef __bf16 bf16x8 __attribute__((ext_vector_type(8)));
typedef float  f32x4  __attribute__((ext_vector_type(4)));

// ---------------------------------------------------------------------------
// NT GEMM: C[M,N] = A[M,K] * W[N,K]^T   (both A and W are K-contiguous)
// 64x64 tile, BK=16, 256 threads, 4x4 micro-tile per thread. fp32.
// ---------------------------------------------------------------------------
__global__ __launch_bounds__(256) void gemm_nt(const float* __restrict__ A,
                                               const float* __restrict__ W,
                                               float* __restrict__ C,
                                               int M, int N, int K) {
    __shared__ float As[64][17];
    __shared__ float Ws[64][17];

    const int t  = threadIdx.x;
    const int tx = t & 15;        // 0..15 -> N direction
    const int ty = t >> 4;        // 0..15 -> M direction
    const int m0 = blockIdx.y * 64;
    const int n0 = blockIdx.x * 64;

    const int lr = t >> 2;        // 0..63 (tile row for loading)
    const int lc = (t & 3) * 4;   // 0,4,8,12 (k-col for loading, float4)

    float acc[4][4] = {};

    for (int k0 = 0; k0 < K; k0 += 16) {
        float4 av = *reinterpret_cast<const float4*>(&A[(size_t)(m0 + lr) * K + k0 + lc]);
        float4 wv = *reinterpret_cast<const float4*>(&W[(size_t)(n0 + lr) * K + k0 + lc]);
        As[lr][lc + 0] = av.x; As[lr][lc + 1] = av.y;
        As[lr][lc + 2] = av.z; As[lr][lc + 3] = av.w;
        Ws[lr][lc + 0] = wv.x; Ws[lr][lc + 1] = wv.y;
        Ws[lr][lc + 2] = wv.z; Ws[lr][lc + 3] = wv.w;
        __syncthreads();

        #pragma unroll
        for (int kk = 0; kk < 16; kk++) {
            float a[4], w[4];
            #pragma unroll
            for (int i = 0; i < 4; i++) a[i] = As[ty * 4 + i][kk];
            #pragma unroll
            for (int j = 0; j < 4; j++) w[j] = Ws[tx * 4 + j][kk];
            #pragma unroll
            for (int i = 0; i < 4; i++)
                #pragma unroll
                for (int j = 0; j < 4; j++)
                    acc[i][j] = fmaf(a[i], w[j], acc[i][j]);
        }
        __syncthreads();
    }

    #pragma unroll
    for (int i = 0; i < 4; i++) {
        #pragma unroll
        for (int j = 0; j < 4; j++) {
            C[(size_t)(m0 + ty * 4 + i) * N + n0 + tx * 4 + j] = acc[i][j];
        }
    }
}

// ---------------------------------------------------------------------------
// Fused per-head RMSNorm + RoPE (in-place on the projected q or k buffer).
// One 128-thread block per (b*s, head). buf layout: [BS, nheads*HD].
// ---------------------------------------------------------------------------
__global__ __launch_bounds__(128) void norm_rope(float* __restrict__ buf,
                                                 const float* __restrict__ w,
                                                 int nheads) {
    __shared__ float sred[2];
    __shared__ float nv[128];

    const int row  = blockIdx.x;          // b*S + s
    const int s    = row & (S_ - 1);      // position
    const int head = blockIdx.y;
    const int d    = threadIdx.x;

    float* p = buf + (size_t)row * nheads * HD_ + (size_t)head * HD_;
    float x = p[d];

    // sum of squares over 128 elems (2 waves)
    float ss = x * x;
    #pragma unroll
    for (int off = 32; off; off >>= 1) ss += __shfl_xor(ss, off);
    if ((threadIdx.x & 63) == 0) sred[threadIdx.x >> 6] = ss;
    __syncthreads();
    float mean = (sred[0] + sred[1]) * (1.0f / 128.0f);
    float rs = rsqrtf(mean + 1e-6f);

    float n = x * rs * w[d];
    nv[d] = n;
    __syncthreads();

    const int i = d & 63;
    // inv_freq = THETA^(-2i/128) ; log(1e6) = 13.815510557964274
    float inv_freq = expf(-13.815510557964274f * (float)(2 * i) * (1.0f / 128.0f));
    float ang = (float)s * inv_freq;
    float sn, cs;
    sincosf(ang, &sn, &cs);

    float other = nv[d ^ 64];
    float r = (d < 64) ? (n * cs - other * sn)   // x1*c - x2*s
                       : (other * sn + n * cs);  // x1*s + x2*c
    p[d] = r;
}

// ---------------------------------------------------------------------------
// MFMA bf16 flash attention (causal, GQA rep=2).
// Grid: (S/64, B*H). Block: 256 threads = 4 waves.
// Block handles 64 q-rows of one (b,h); wave w owns q-rows [w*16, w*16+16).
// Key loop tiles of 64 keys. LDS:
//   Qs[64][136] bf16 (pad->2-way bank aliasing, free)  17408 B
//   Ks[64][136] bf16                                   17408 B
//   Vt[128][72] bf16 (dim-major for PV B-fragments)    18432 B
//   Ps[4][16][72] bf16 (P C-layout -> A-layout bounce)  9216 B
// total 62464 B -> 2 blocks/CU.
// MFMA layouts (m89/m120 verified):
//   A-frag: A[m=lane&15][k=quad*8+j]; B-frag: B[k=quad*8+j][n=lane&15]
//   C/D:    col=lane&15, row=quad*4+reg
// ---------------------------------------------------------------------------
__global__ __launch_bounds__(256) void attn_mfma(const float* __restrict__ Q,
                                                 const float* __restrict__ Kg,
                                                 const float* __restrict__ Vg,
                                                 float* __restrict__ O) {
    __shared__ __bf16 Qs[64][136];
    __shared__ __bf16 Ks[64][136];
    __shared__ __bf16 Vt[128][72];
    __shared__ __bf16 Ps[4][16][72];

    const int t    = threadIdx.x;
    const int w    = t >> 6;
    const int lane = t & 63;
    const int col  = lane & 15;     // n-index inside a 16-wide MFMA tile
    const int quad = lane >> 4;     // 0..3

    const int bh  = blockIdx.y;
    const int b   = bh >> 4;        // / H_
    const int h   = bh & 15;        // % H_
    const int kvh = h >> 1;         // GQA: rep = 2
    const int qb  = gridDim.x - 1 - blockIdx.x;   // big blocks launch first
    const int r0  = qb * 64;

    // ---- stage Q tile (64 rows x 128 dims) as bf16, once ----
    #pragma unroll
    for (int i = 0; i < 8; i++) {
        int f   = t + i * 256;          // 0..2047 float4s
        int row = f >> 5;
        int d4  = (f & 31) * 4;
        const float4 v = *reinterpret_cast<const float4*>(
            &Q[(((size_t)(b * S_ + r0 + row)) * H_ + h) * HD_ + d4]);
        Qs[row][d4 + 0] = (__bf16)v.x;
        Qs[row][d4 + 1] = (__bf16)v.y;
        Qs[row][d4 + 2] = (__bf16)v.z;
        Qs[row][d4 + 3] = (__bf16)v.w;
    }
    __syncthreads();

    // preload this wave's Q A-fragments (rows w*16+col), kept all kernel
    bf16x8 qf[4];
    {
        const int m = w * 16 + col;
        #pragma unroll
        for (int k = 0; k < 4; k++)
            qf[k] = *reinterpret_cast<const bf16x8*>(&Qs[m][k * 32 + quad * 8]);
    }

    f32x4 o_acc[8];
    #pragma unroll
    for (int i = 0; i < 8; i++) o_acc[i] = (f32x4){0.f, 0.f, 0.f, 0.f};
    float m_r[4], l_r[4];
    #pragma unroll
    for (int r = 0; r < 4; r++) { m_r[r] = -INFINITY; l_r[r] = 0.f; }

    const int ntiles = qb + 1;
    for (int ti = 0; ti < ntiles; ti++) {
        const int t0 = ti * 64;
        __syncthreads();   // prior tile's PV reads of Ks/Vt are done

        // ---- stage K (row-major) and V (transposed) tiles as bf16 ----
        #pragma unroll
        for (int i = 0; i < 8; i++) {
            int f   = t + i * 256;
            int row = f >> 5;               // key within tile
            int d4  = (f & 31) * 4;
            size_t g = (((size_t)(b * S_ + t0 + row)) * HK_ + kvh) * HD_ + d4;
            const float4 kv = *reinterpret_cast<const float4*>(&Kg[g]);
            Ks[row][d4 + 0] = (__bf16)kv.x;
            Ks[row][d4 + 1] = (__bf16)kv.y;
            Ks[row][d4 + 2] = (__bf16)kv.z;
            Ks[row][d4 + 3] = (__bf16)kv.w;
            const float4 vv = *reinterpret_cast<const float4*>(&Vg[g]);
            Vt[d4 + 0][row] = (__bf16)vv.x;
            Vt[d4 + 1][row] = (__bf16)vv.y;
            Vt[d4 + 2][row] = (__bf16)vv.z;
            Vt[d4 + 3][row] = (__bf16)vv.w;
        }
        __syncthreads();

        // ---- S = Q K^T : 16 q-rows x 64 keys per wave ----
        f32x4 s[4];
        #pragma unroll
        for (int n = 0; n < 4; n++) {
            f32x4 acc = (f32x4){0.f, 0.f, 0.f, 0.f};
            #pragma unroll
            for (int k = 0; k < 4; k++) {
                bf16x8 bf = *reinterpret_cast<const bf16x8*>(
                    &Ks[n * 16 + col][k * 32 + quad * 8]);
                acc = __builtin_amdgcn_mfma_f32_16x16x32_bf16(qf[k], bf, acc, 0, 0, 0);
            }
            s[n] = acc;
        }

        // ---- online softmax (rows = quad*4+r, cols = n*16+col) ----
        const bool diag = (t0 == r0);
        float p[4][4];     // [ntile][reg]
        float alpha[4];
        #pragma unroll
        for (int r = 0; r < 4; r++) {
            float v0 = s[0][r] * SCALE, v1 = s[1][r] * SCALE;
            float v2 = s[2][r] * SCALE, v3 = s[3][r] * SCALE;
            if (diag) {
                int qloc = w * 16 + quad * 4 + r;   // local q row == local causal bound
                if (0 * 16 + col > qloc) v0 = -INFINITY;
                if (1 * 16 + col > qloc) v1 = -INFINITY;
                if (2 * 16 + col > qloc) v2 = -INFINITY;
                if (3 * 16 + col > qloc) v3 = -INFINITY;
            }
            float mx = fmaxf(fmaxf(v0, v1), fmaxf(v2, v3));
            #pragma unroll
            for (int off = 8; off; off >>= 1) mx = fmaxf(mx, __shfl_xor(mx, off));
            float mn = fmaxf(m_r[r], mx);
            float al = __expf(m_r[r] - mn);
            float p0 = __expf(v0 - mn);
            float p1 = __expf(v1 - mn);
            float p2 = __expf(v2 - mn);
            float p3 = __expf(v3 - mn);
            float ts = p0 + p1 + p2 + p3;
            #pragma unroll
            for (int off = 8; off; off >>= 1) ts += __shfl_xor(ts, off);
            l_r[r] = l_r[r] * al + ts;
            m_r[r] = mn;
            alpha[r] = al;
            p[0][r] = p0; p[1][r] = p1; p[2][r] = p2; p[3][r] = p3;
        }

        // write P (own wave's slice; same-wave RAW -> no barrier needed)
        #pragma unroll
        for (int n = 0; n < 4; n++)
            #pragma unroll
            for (int r = 0; r < 4; r++)
                Ps[w][quad * 4 + r][n * 16 + col] = (__bf16)p[n][r];

        // rescale O accumulator
        #pragma unroll
        for (int n = 0; n < 8; n++)
            #pragma unroll
            for (int r = 0; r < 4; r++)
                o_acc[n][r] *= alpha[r];

        // ---- PV: O += P * V ----
        bf16x8 pf[2];
        #pragma unroll
        for (int ks = 0; ks < 2; ks++)
            pf[ks] = *reinterpret_cast<const bf16x8*>(&Ps[w][col][ks * 32 + quad * 8]);
        #pragma unroll
        for (int n = 0; n < 8; n++) {
            #pragma unroll
            for (int ks = 0; ks < 2; ks++) {
                bf16x8 vf = *reinterpret_cast<const bf16x8*>(
                    &Vt[n * 16 + col][ks * 32 + quad * 8]);
                o_acc[n] = __builtin_amdgcn_mfma_f32_16x16x32_bf16(pf[ks], vf, o_acc[n], 0, 0, 0);
            }
        }
    }

    // ---- epilogue: O = acc / l ----
    #pragma unroll
    for (int r = 0; r < 4; r++) {
        float inv = 1.0f / l_r[r];
        int qrow = r0 + w * 16 + quad * 4 + r;
        size_t base = (((size_t)(b * S_ + qrow)) * H_ + h) * HD_;
        #pragma unroll
        for (int n = 0; n < 8; n++)
            O[base + n * 16 + col] = o_acc[n][r] * inv;
    }
}

// ---------------------------------------------------------------------------
extern "C" void kernel_launch(void* const* d_in, const int* in_sizes, int n_in,
                              void* d_out, int out_size, void* d_ws, size_t ws_size,
                              hipStream_t stream) {
    const float* x  = (const float*)d_in[0];
    const float* wq = (const float*)d_in[1];
    const float* wk = (const float*)d_in[2];
    const float* wv = (const float*)d_in[3];
    const float* wo = (const float*)d_in[4];
    const float* qw = (const float*)d_in[5];
    const float* kw = (const float*)d_in[6];
    float* out = (float*)d_out;

    float* ws   = (float*)d_ws;
    float* q    = ws;                                  // BS * H*HD  = 8388608
    float* kbuf = q    + (size_t)BS_ * H_  * HD_;      // BS * HK*HD = 4194304
    float* vbuf = kbuf + (size_t)BS_ * HK_ * HD_;      // BS * HK*HD = 4194304
    float* ao   = vbuf + (size_t)BS_ * HK_ * HD_;      // BS * H*HD  = 8388608
    // total: 25165824 floats = ~101 MB of d_ws

    // QKV projections
    gemm_nt<<<dim3((H_ * HD_) / 64, BS_ / 64), 256, 0, stream>>>(x, wq, q,    BS_, H_ * HD_,  D_);
    gemm_nt<<<dim3((HK_ * HD_) / 64, BS_ / 64), 256, 0, stream>>>(x, wk, kbuf, BS_, HK_ * HD_, D_);
    gemm_nt<<<dim3((HK_ * HD_) / 64, BS_ / 64), 256, 0, stream>>>(x, wv, vbuf, BS_, HK_ * HD_, D_);

    // RMSNorm + RoPE on q and k
    norm_rope<<<dim3(BS_, H_),  128, 0, stream>>>(q,    qw, H_);
    norm_rope<<<dim3(BS_, HK_), 128, 0, stream>>>(kbuf, kw, HK_);

    // Causal GQA attention (MFMA bf16 flash)
    attn_mfma<<<dim3(S_ / 64, B_ * H_), 256, 0, stream>>>(q, kbuf, vbuf, ao);

    // Output projection
    gemm_nt<<<dim3(D_ / 64, BS_ / 64), 256, 0, stream>>>(ao, wo, out, BS_, D_, H_ * HD_);
}

// Round 3
// 703.484 us; speedup vs baseline: 11.8567x; 3.7190x over previous
//
#include <hip/hip_runtime.h>
#include <hip/hip_bf16.h>
#include <math.h>

// Problem constants (Qwen3-style attention block)
#define B_   2
#define S_   2048
#define D_   2048
#define H_   16
#define HK_  8
#define HD_  128
#define BS_  (B_ * S_)          // 4096 rows
#define NQKV 4096               // combined q(2048) + k(1024) + v(1024) cols
#define SCALE 0.08838834764831845f  // 1/sqrt(128)

typedef __bf16 bf16x8 __attribute__((ext_vector_type(8)));
typedef __bf16 bf16x4 __attribute__((ext_vector_type(4)));
typedef float  f32x4  __attribute__((ext_vector_type(4)));

#define AS1(p) ((const __attribute__((address_space(1))) void*)(p))
#define AS3(p) ((__attribute__((address_space(3))) void*)(p))

// ---------------------------------------------------------------------------
// fp32 -> bf16 convert (vectorized, one float4 -> bf16x4 per thread)
// ---------------------------------------------------------------------------
__global__ __launch_bounds__(256) void cvt_bf16(const float* __restrict__ in,
                                                __bf16* __restrict__ out, int n4) {
    int i = blockIdx.x * 256 + threadIdx.x;
    if (i < n4) {
        float4 v = reinterpret_cast<const float4*>(in)[i];
        bf16x4 o = {(__bf16)v.x, (__bf16)v.y, (__bf16)v.z, (__bf16)v.w};
        reinterpret_cast<bf16x4*>(out)[i] = o;
    }
}

// ---------------------------------------------------------------------------
// bf16 MFMA NT GEMM (m97 structure): C[M,N] = A[M,K] * W[N,K]^T
// 128x128 tile, BK=32, 256 threads = 4 waves (2x2), 16 MFMA 16x16x32 per
// K-iter, global_load_lds width=16 staging, no LDS padding.
// ---------------------------------------------------------------------------
template <typename CT>
__global__ __launch_bounds__(256) void gemm_bf16_nt(const __bf16* __restrict__ A,
                                                    const __bf16* __restrict__ W,
                                                    CT* __restrict__ C,
                                                    int M, int N, int K) {
    __shared__ __bf16 As[128 * 32];
    __shared__ __bf16 Bs[128 * 32];

    const int t    = threadIdx.x;
    const int w    = t >> 6;
    const int lane = t & 63;
    const int col  = lane & 15;
    const int quad = lane >> 4;
    const int wm   = w >> 1;      // 0..1 (M half)
    const int wn   = w & 1;       // 0..1 (N half)

    const int m0 = blockIdx.y * 128;
    const int n0 = blockIdx.x * 128;

    // staging: wave w covers tile rows [w*32, w*32+32), 2 issues of 16 rows.
    const int lrow = lane >> 2;          // 0..15
    const int lk   = (lane & 3) * 8;     // bf16 elem offset within BK=32

    const __bf16* agp = A + (size_t)(m0 + w * 32 + lrow) * K + lk;
    const __bf16* wgp = W + (size_t)(n0 + w * 32 + lrow) * K + lk;
    __bf16* alp = As + (w * 32) * 32;    // wave-uniform LDS bases
    __bf16* blp = Bs + (w * 32) * 32;

    f32x4 acc[4][4];
    #pragma unroll
    for (int m = 0; m < 4; m++)
        #pragma unroll
        for (int n = 0; n < 4; n++) acc[m][n] = (f32x4){0.f, 0.f, 0.f, 0.f};

    #pragma unroll 1
    for (int k0 = 0; k0 < K; k0 += 32) {
        __builtin_amdgcn_global_load_lds(AS1(agp + k0),                    AS3(alp),            16, 0, 0);
        __builtin_amdgcn_global_load_lds(AS1(agp + k0 + (size_t)16 * K),   AS3(alp + 16 * 32),  16, 0, 0);
        __builtin_amdgcn_global_load_lds(AS1(wgp + k0),                    AS3(blp),            16, 0, 0);
        __builtin_amdgcn_global_load_lds(AS1(wgp + k0 + (size_t)16 * K),   AS3(blp + 16 * 32),  16, 0, 0);
        __syncthreads();

        bf16x8 af[4], bfr[4];
        #pragma unroll
        for (int m = 0; m < 4; m++)
            af[m] = *reinterpret_cast<const bf16x8*>(&As[(wm * 64 + m * 16 + col) * 32 + quad * 8]);
        #pragma unroll
        for (int n = 0; n < 4; n++)
            bfr[n] = *reinterpret_cast<const bf16x8*>(&Bs[(wn * 64 + n * 16 + col) * 32 + quad * 8]);

        #pragma unroll
        for (int m = 0; m < 4; m++)
            #pragma unroll
            for (int n = 0; n < 4; n++)
                acc[m][n] = __builtin_amdgcn_mfma_f32_16x16x32_bf16(af[m], bfr[n], acc[m][n], 0, 0, 0);
        __syncthreads();
    }

    // epilogue: C/D layout col=lane&15, row=quad*4+reg
    #pragma unroll
    for (int m = 0; m < 4; m++) {
        #pragma unroll
        for (int r = 0; r < 4; r++) {
            size_t row = m0 + wm * 64 + m * 16 + quad * 4 + r;
            CT* cp = C + row * N + n0 + wn * 64 + col;
            #pragma unroll
            for (int n = 0; n < 4; n++) cp[n * 16] = (CT)acc[m][n][r];
        }
    }
}

// ---------------------------------------------------------------------------
// Fused per-head RMSNorm + RoPE, in-place on bf16 qkv buffer.
// base points at the q or k sub-block; row stride NQKV.
// ---------------------------------------------------------------------------
__global__ __launch_bounds__(128) void norm_rope(__bf16* __restrict__ base,
                                                 const float* __restrict__ w) {
    __shared__ float sred[2];
    __shared__ float nv[128];

    const int row  = blockIdx.x;          // b*S + s
    const int s    = row & (S_ - 1);      // position
    const int head = blockIdx.y;
    const int d    = threadIdx.x;

    __bf16* p = base + (size_t)row * NQKV + (size_t)head * HD_;
    float x = (float)p[d];

    float ss = x * x;
    #pragma unroll
    for (int off = 32; off; off >>= 1) ss += __shfl_xor(ss, off);
    if ((threadIdx.x & 63) == 0) sred[threadIdx.x >> 6] = ss;
    __syncthreads();
    float mean = (sred[0] + sred[1]) * (1.0f / 128.0f);
    float rs = rsqrtf(mean + 1e-6f);

    float n = x * rs * w[d];
    nv[d] = n;
    __syncthreads();

    const int i = d & 63;
    float inv_freq = expf(-13.815510557964274f * (float)(2 * i) * (1.0f / 128.0f));
    float ang = (float)s * inv_freq;
    float sn, cs;
    sincosf(ang, &sn, &cs);

    float other = nv[d ^ 64];
    float r = (d < 64) ? (n * cs - other * sn)
                       : (other * sn + n * cs);
    p[d] = (__bf16)r;
}

// ---------------------------------------------------------------------------
// MFMA bf16 flash attention (causal, GQA rep=2), reading the combined bf16
// qkv buffer [BS][NQKV] (q at col 0, k at 2048, v at 3072), writing bf16 ao.
// Grid: (S/64, B*H). Block: 256 threads = 4 waves; wave owns 16 q-rows.
// ---------------------------------------------------------------------------
__global__ __launch_bounds__(256) void attn_mfma(const __bf16* __restrict__ qkv,
                                                 __bf16* __restrict__ ao) {
    __shared__ __bf16 Qs[64][136];
    __shared__ __bf16 Ks[64][136];
    __shared__ __bf16 Vt[128][72];
    __shared__ __bf16 Ps[4][16][72];

    const int t    = threadIdx.x;
    const int w    = t >> 6;
    const int lane = t & 63;
    const int col  = lane & 15;
    const int quad = lane >> 4;

    const int bh  = blockIdx.y;
    const int b   = bh >> 4;
    const int h   = bh & 15;
    const int kvh = h >> 1;
    const int qb  = gridDim.x - 1 - blockIdx.x;   // big blocks first
    const int r0  = qb * 64;

    // ---- stage Q tile (64 rows x 128) ----
    #pragma unroll
    for (int i = 0; i < 4; i++) {
        int f   = t + i * 256;          // chunk index, 16 chunks/row
        int row = f >> 4;
        int d8  = (f & 15) * 8;
        bf16x8 v = *reinterpret_cast<const bf16x8*>(
            &qkv[(size_t)(b * S_ + r0 + row) * NQKV + h * HD_ + d8]);
        *reinterpret_cast<bf16x8*>(&Qs[row][d8]) = v;
    }
    __syncthreads();

    bf16x8 qf[4];
    {
        const int m = w * 16 + col;
        #pragma unroll
        for (int k = 0; k < 4; k++)
            qf[k] = *reinterpret_cast<const bf16x8*>(&Qs[m][k * 32 + quad * 8]);
    }

    f32x4 o_acc[8];
    #pragma unroll
    for (int i = 0; i < 8; i++) o_acc[i] = (f32x4){0.f, 0.f, 0.f, 0.f};
    float m_r[4], l_r[4];
    #pragma unroll
    for (int r = 0; r < 4; r++) { m_r[r] = -INFINITY; l_r[r] = 0.f; }

    const int ntiles = qb + 1;
    for (int ti = 0; ti < ntiles; ti++) {
        const int t0 = ti * 64;
        __syncthreads();

        // ---- stage K (row-major) + V (transposed) ----
        #pragma unroll
        for (int i = 0; i < 4; i++) {
            int f   = t + i * 256;
            int row = f >> 4;
            int d8  = (f & 15) * 8;
            size_t g = (size_t)(b * S_ + t0 + row) * NQKV + kvh * HD_ + d8;
            bf16x8 kv = *reinterpret_cast<const bf16x8*>(&qkv[g + 2048]);
            *reinterpret_cast<bf16x8*>(&Ks[row][d8]) = kv;
            bf16x8 vv = *reinterpret_cast<const bf16x8*>(&qkv[g + 3072]);
            #pragma unroll
            for (int e = 0; e < 8; e++) Vt[d8 + e][row] = vv[e];
        }
        __syncthreads();

        // ---- S = Q K^T ----
        f32x4 s[4];
        #pragma unroll
        for (int n = 0; n < 4; n++) {
            f32x4 acc = (f32x4){0.f, 0.f, 0.f, 0.f};
            #pragma unroll
            for (int k = 0; k < 4; k++) {
                bf16x8 bf = *reinterpret_cast<const bf16x8*>(
                    &Ks[n * 16 + col][k * 32 + quad * 8]);
                acc = __builtin_amdgcn_mfma_f32_16x16x32_bf16(qf[k], bf, acc, 0, 0, 0);
            }
            s[n] = acc;
        }

        // ---- online softmax (rows = quad*4+r, cols = n*16+col) ----
        const bool diag = (t0 == r0);
        float p[4][4];
        float alpha[4];
        #pragma unroll
        for (int r = 0; r < 4; r++) {
            float v0 = s[0][r] * SCALE, v1 = s[1][r] * SCALE;
            float v2 = s[2][r] * SCALE, v3 = s[3][r] * SCALE;
            if (diag) {
                int qloc = w * 16 + quad * 4 + r;
                if (0 * 16 + col > qloc) v0 = -INFINITY;
                if (1 * 16 + col > qloc) v1 = -INFINITY;
                if (2 * 16 + col > qloc) v2 = -INFINITY;
                if (3 * 16 + col > qloc) v3 = -INFINITY;
            }
            float mx = fmaxf(fmaxf(v0, v1), fmaxf(v2, v3));
            #pragma unroll
            for (int off = 8; off; off >>= 1) mx = fmaxf(mx, __shfl_xor(mx, off));
            float mn = fmaxf(m_r[r], mx);
            float al = __expf(m_r[r] - mn);
            float p0 = __expf(v0 - mn);
            float p1 = __expf(v1 - mn);
            float p2 = __expf(v2 - mn);
            float p3 = __expf(v3 - mn);
            float ts = p0 + p1 + p2 + p3;
            #pragma unroll
            for (int off = 8; off; off >>= 1) ts += __shfl_xor(ts, off);
            l_r[r] = l_r[r] * al + ts;
            m_r[r] = mn;
            alpha[r] = al;
            p[0][r] = p0; p[1][r] = p1; p[2][r] = p2; p[3][r] = p3;
        }

        #pragma unroll
        for (int n = 0; n < 4; n++)
            #pragma unroll
            for (int r = 0; r < 4; r++)
                Ps[w][quad * 4 + r][n * 16 + col] = (__bf16)p[n][r];

        #pragma unroll
        for (int n = 0; n < 8; n++)
            #pragma unroll
            for (int r = 0; r < 4; r++)
                o_acc[n][r] *= alpha[r];

        // ---- PV ----
        bf16x8 pf[2];
        #pragma unroll
        for (int ks = 0; ks < 2; ks++)
            pf[ks] = *reinterpret_cast<const bf16x8*>(&Ps[w][col][ks * 32 + quad * 8]);
        #pragma unroll
        for (int n = 0; n < 8; n++) {
            #pragma unroll
            for (int ks = 0; ks < 2; ks++) {
                bf16x8 vf = *reinterpret_cast<const bf16x8*>(
                    &Vt[n * 16 + col][ks * 32 + quad * 8]);
                o_acc[n] = __builtin_amdgcn_mfma_f32_16x16x32_bf16(pf[ks], vf, o_acc[n], 0, 0, 0);
            }
        }
    }

    // ---- epilogue: ao (bf16, [BS][2048], head-major) ----
    #pragma unroll
    for (int r = 0; r < 4; r++) {
        float inv = 1.0f / l_r[r];
        int qrow = r0 + w * 16 + quad * 4 + r;
        __bf16* op = ao + (size_t)(b * S_ + qrow) * (H_ * HD_) + h * HD_ + col;
        #pragma unroll
        for (int n = 0; n < 8; n++)
            op[n * 16] = (__bf16)(o_acc[n][r] * inv);
    }
}

// ---------------------------------------------------------------------------
extern "C" void kernel_launch(void* const* d_in, const int* in_sizes, int n_in,
                              void* d_out, int out_size, void* d_ws, size_t ws_size,
                              hipStream_t stream) {
    const float* x  = (const float*)d_in[0];
    const float* wq = (const float*)d_in[1];
    const float* wk = (const float*)d_in[2];
    const float* wv = (const float*)d_in[3];
    const float* wo = (const float*)d_in[4];
    const float* qw = (const float*)d_in[5];
    const float* kw = (const float*)d_in[6];
    float* out = (float*)d_out;

    // workspace (bf16 elements), total 46.1M elems = 92.3 MB
    __bf16* ws  = (__bf16*)d_ws;
    __bf16* xb  = ws;                               // [4096][2048]  8.4M
    __bf16* wb  = xb  + (size_t)8388608;            // [4096][2048]  8.4M (wq|wk|wv)
    __bf16* wob = wb  + (size_t)8388608;            // [2048][2048]  4.2M
    __bf16* qkv = wob + (size_t)4194304;            // [4096][4096] 16.8M
    __bf16* ao  = qkv + (size_t)16777216;           // [4096][2048]  8.4M

    // fp32 -> bf16 converts
    cvt_bf16<<<2097152 / 256, 256, 0, stream>>>(x,  xb,  2097152);
    cvt_bf16<<<1048576 / 256, 256, 0, stream>>>(wq, wb,  1048576);
    cvt_bf16<<< 524288 / 256, 256, 0, stream>>>(wk, wb + (size_t)2048 * 2048, 524288);
    cvt_bf16<<< 524288 / 256, 256, 0, stream>>>(wv, wb + (size_t)3072 * 2048, 524288);
    cvt_bf16<<<1048576 / 256, 256, 0, stream>>>(wo, wob, 1048576);

    // fused QKV projection: qkv[BS][4096] = xb * [wq|wk|wv]^T
    gemm_bf16_nt<__bf16><<<dim3(NQKV / 128, BS_ / 128), 256, 0, stream>>>(
        xb, wb, qkv, BS_, NQKV, D_);

    // RMSNorm + RoPE on q (16 heads) and k (8 heads)
    norm_rope<<<dim3(BS_, H_),  128, 0, stream>>>(qkv,        qw);
    norm_rope<<<dim3(BS_, HK_), 128, 0, stream>>>(qkv + 2048, kw);

    // causal GQA attention
    attn_mfma<<<dim3(S_ / 64, B_ * H_), 256, 0, stream>>>(qkv, ao);

    // output projection: out[BS][2048] = ao * wo^T  (fp32 out)
    gemm_bf16_nt<float><<<dim3(D_ / 128, BS_ / 128), 256, 0, stream>>>(
        ao, wob, out, BS_, D_, H_ * HD_);
}

// Round 4
// 621.610 us; speedup vs baseline: 13.4183x; 1.1317x over previous
//
#include <hip/hip_runtime.h>
#include <hip/hip_bf16.h>
#include <math.h>

// Problem constants (Qwen3-style attention block)
#define B_   2
#define S_   2048
#define D_   2048
#define H_   16
#define HK_  8
#define HD_  128
#define BS_  (B_ * S_)          // 4096 rows
#define NQKV 4096               // combined q(2048) + k(1024) + v(1024) cols
#define SCALE 0.08838834764831845f  // 1/sqrt(128)

typedef __bf16 bf16x8 __attribute__((ext_vector_type(8)));
typedef __bf16 bf16x4 __attribute__((ext_vector_type(4)));
typedef float  f32x4  __attribute__((ext_vector_type(4)));

#define AS1(p) ((const __attribute__((address_space(1))) void*)(p))
#define AS3(p) ((__attribute__((address_space(3))) void*)(p))

// ---------------------------------------------------------------------------
// fp32 -> bf16 convert
// ---------------------------------------------------------------------------
__global__ __launch_bounds__(256) void cvt_bf16(const float* __restrict__ in,
                                                __bf16* __restrict__ out, int n4) {
    int i = blockIdx.x * 256 + threadIdx.x;
    if (i < n4) {
        float4 v = reinterpret_cast<const float4*>(in)[i];
        bf16x4 o = {(__bf16)v.x, (__bf16)v.y, (__bf16)v.z, (__bf16)v.w};
        reinterpret_cast<bf16x4*>(out)[i] = o;
    }
}

// ---------------------------------------------------------------------------
// bf16 MFMA NT GEMM (m97 structure): C[M,N] = A[M,K] * W[N,K]^T
// ---------------------------------------------------------------------------
template <typename CT>
__global__ __launch_bounds__(256) void gemm_bf16_nt(const __bf16* __restrict__ A,
                                                    const __bf16* __restrict__ W,
                                                    CT* __restrict__ C,
                                                    int M, int N, int K) {
    __shared__ __bf16 As[128 * 32];
    __shared__ __bf16 Bs[128 * 32];

    const int t    = threadIdx.x;
    const int w    = t >> 6;
    const int lane = t & 63;
    const int col  = lane & 15;
    const int quad = lane >> 4;
    const int wm   = w >> 1;
    const int wn   = w & 1;

    const int m0 = blockIdx.y * 128;
    const int n0 = blockIdx.x * 128;

    const int lrow = lane >> 2;
    const int lk   = (lane & 3) * 8;

    const __bf16* agp = A + (size_t)(m0 + w * 32 + lrow) * K + lk;
    const __bf16* wgp = W + (size_t)(n0 + w * 32 + lrow) * K + lk;
    __bf16* alp = As + (w * 32) * 32;
    __bf16* blp = Bs + (w * 32) * 32;

    f32x4 acc[4][4];
    #pragma unroll
    for (int m = 0; m < 4; m++)
        #pragma unroll
        for (int n = 0; n < 4; n++) acc[m][n] = (f32x4){0.f, 0.f, 0.f, 0.f};

    #pragma unroll 1
    for (int k0 = 0; k0 < K; k0 += 32) {
        __builtin_amdgcn_global_load_lds(AS1(agp + k0),                  AS3(alp),           16, 0, 0);
        __builtin_amdgcn_global_load_lds(AS1(agp + k0 + (size_t)16 * K), AS3(alp + 16 * 32), 16, 0, 0);
        __builtin_amdgcn_global_load_lds(AS1(wgp + k0),                  AS3(blp),           16, 0, 0);
        __builtin_amdgcn_global_load_lds(AS1(wgp + k0 + (size_t)16 * K), AS3(blp + 16 * 32), 16, 0, 0);
        __syncthreads();

        bf16x8 af[4], bfr[4];
        #pragma unroll
        for (int m = 0; m < 4; m++)
            af[m] = *reinterpret_cast<const bf16x8*>(&As[(wm * 64 + m * 16 + col) * 32 + quad * 8]);
        #pragma unroll
        for (int n = 0; n < 4; n++)
            bfr[n] = *reinterpret_cast<const bf16x8*>(&Bs[(wn * 64 + n * 16 + col) * 32 + quad * 8]);

        #pragma unroll
        for (int m = 0; m < 4; m++)
            #pragma unroll
            for (int n = 0; n < 4; n++)
                acc[m][n] = __builtin_amdgcn_mfma_f32_16x16x32_bf16(af[m], bfr[n], acc[m][n], 0, 0, 0);
        __syncthreads();
    }

    #pragma unroll
    for (int m = 0; m < 4; m++) {
        #pragma unroll
        for (int r = 0; r < 4; r++) {
            size_t row = m0 + wm * 64 + m * 16 + quad * 4 + r;
            CT* cp = C + row * N + n0 + wn * 64 + col;
            #pragma unroll
            for (int n = 0; n < 4; n++) cp[n * 16] = (CT)acc[m][n][r];
        }
    }
}

// ---------------------------------------------------------------------------
// Fused per-head RMSNorm + RoPE, in-place on bf16 qkv buffer.
// ---------------------------------------------------------------------------
__global__ __launch_bounds__(128) void norm_rope(__bf16* __restrict__ base,
                                                 const float* __restrict__ w) {
    __shared__ float sred[2];
    __shared__ float nv[128];

    const int row  = blockIdx.x;
    const int s    = row & (S_ - 1);
    const int head = blockIdx.y;
    const int d    = threadIdx.x;

    __bf16* p = base + (size_t)row * NQKV + (size_t)head * HD_;
    float x = (float)p[d];

    float ss = x * x;
    #pragma unroll
    for (int off = 32; off; off >>= 1) ss += __shfl_xor(ss, off);
    if ((threadIdx.x & 63) == 0) sred[threadIdx.x >> 6] = ss;
    __syncthreads();
    float mean = (sred[0] + sred[1]) * (1.0f / 128.0f);
    float rs = rsqrtf(mean + 1e-6f);

    float n = x * rs * w[d];
    nv[d] = n;
    __syncthreads();

    const int i = d & 63;
    float inv_freq = expf(-13.815510557964274f * (float)(2 * i) * (1.0f / 128.0f));
    float ang = (float)s * inv_freq;
    float sn, cs;
    sincosf(ang, &sn, &cs);

    float other = nv[d ^ 64];
    float r = (d < 64) ? (n * cs - other * sn)
                       : (other * sn + n * cs);
    p[d] = (__bf16)r;
}

// ---------------------------------------------------------------------------
// V transpose: vt[(b*HK+kvh)*128 + dim][s] = v[b*S+s][kvh*128+dim]
// Grid (S/64, B*HK), 256 threads, LDS bounce 64x136.
// ---------------------------------------------------------------------------
__global__ __launch_bounds__(256) void transpose_v(const __bf16* __restrict__ qkv,
                                                   __bf16* __restrict__ vt) {
    __shared__ __bf16 Ls[64][136];
    const int t  = threadIdx.x;
    const int bk = blockIdx.y;            // b*8 + kvh
    const int b  = bk >> 3;
    const int kvh = bk & 7;
    const int s0 = blockIdx.x * 64;

    #pragma unroll
    for (int i = 0; i < 4; i++) {
        int f = t + i * 256;
        int row = f >> 4;
        int d8 = (f & 15) * 8;
        bf16x8 v = *reinterpret_cast<const bf16x8*>(
            &qkv[(size_t)(b * S_ + s0 + row) * NQKV + 3072 + kvh * HD_ + d8]);
        *reinterpret_cast<bf16x8*>(&Ls[row][d8]) = v;
    }
    __syncthreads();

    #pragma unroll
    for (int i = 0; i < 4; i++) {
        int f = t + i * 256;
        int dim = f >> 3;
        int kc = f & 7;
        bf16x8 o;
        #pragma unroll
        for (int e = 0; e < 8; e++) o[e] = Ls[kc * 8 + e][dim];
        *reinterpret_cast<bf16x8*>(
            &vt[((size_t)bk * HD_ + dim) * S_ + s0 + kc * 8]) = o;
    }
}

// ---------------------------------------------------------------------------
// MFMA bf16 flash attention (causal, GQA rep=2).
// Grid: (S/128, B*H). Block: 256 threads = 4 waves.
// Block handles 128 q-rows of one (b,h); wave w owns rows [w*32, w*32+32)
// as 2 m-tiles of 16. K tiles of 64 keys from qkv; V tiles from global vt.
// LDS: union{ Qs[128][136] | Ks[64][136]+Vt[128][72] } = 35840 B
//      + Ps[4][32][72] = 18432 B  -> 54272 B total.
// ---------------------------------------------------------------------------
__global__ __launch_bounds__(256) void attn_mfma(const __bf16* __restrict__ qkv,
                                                 const __bf16* __restrict__ vt,
                                                 __bf16* __restrict__ ao) {
    __shared__ __align__(16) char smem[35840];
    __bf16 (*Qs)[136] = reinterpret_cast<__bf16(*)[136]>(smem);
    __bf16 (*Ks)[136] = reinterpret_cast<__bf16(*)[136]>(smem);
    __bf16 (*Vt)[72]  = reinterpret_cast<__bf16(*)[72]>(smem + 17408);
    __shared__ __bf16 Ps[4][32][72];

    const int t    = threadIdx.x;
    const int w    = t >> 6;
    const int lane = t & 63;
    const int col  = lane & 15;
    const int quad = lane >> 4;

    const int bh  = blockIdx.y;
    const int b   = bh >> 4;
    const int h   = bh & 15;
    const int kvh = h >> 1;
    const int qb  = gridDim.x - 1 - blockIdx.x;   // big blocks first
    const int r0  = qb * 128;

    const __bf16* vbase = vt + ((size_t)(b * HK_ + kvh) * HD_) * S_;

    // ---- stage Q tile (128 rows x 128) into overlay, grab fragments ----
    #pragma unroll
    for (int i = 0; i < 8; i++) {
        int f   = t + i * 256;
        int row = f >> 4;
        int d8  = (f & 15) * 8;
        bf16x8 v = *reinterpret_cast<const bf16x8*>(
            &qkv[(size_t)(b * S_ + r0 + row) * NQKV + h * HD_ + d8]);
        *reinterpret_cast<bf16x8*>(&Qs[row][d8]) = v;
    }
    __syncthreads();

    bf16x8 qf[2][4];
    #pragma unroll
    for (int mt = 0; mt < 2; mt++) {
        const int m = w * 32 + mt * 16 + col;
        #pragma unroll
        for (int k = 0; k < 4; k++)
            qf[mt][k] = *reinterpret_cast<const bf16x8*>(&Qs[m][k * 32 + quad * 8]);
    }

    f32x4 o_acc[2][8];
    #pragma unroll
    for (int mt = 0; mt < 2; mt++)
        #pragma unroll
        for (int i = 0; i < 8; i++) o_acc[mt][i] = (f32x4){0.f, 0.f, 0.f, 0.f};
    float m_r[2][4], l_r[2][4];
    #pragma unroll
    for (int mt = 0; mt < 2; mt++)
        #pragma unroll
        for (int r = 0; r < 4; r++) { m_r[mt][r] = -INFINITY; l_r[mt][r] = 0.f; }

    const int ntiles = 2 * qb + 2;
    for (int ti = 0; ti < ntiles; ti++) {
        const int t0 = ti * 64;
        __syncthreads();   // protects qf reads (iter 0) / prior-tile LDS reads

        // ---- stage K tile (64 keys x 128 dims) ----
        #pragma unroll
        for (int i = 0; i < 4; i++) {
            int f   = t + i * 256;
            int row = f >> 4;
            int d8  = (f & 15) * 8;
            bf16x8 kv = *reinterpret_cast<const bf16x8*>(
                &qkv[(size_t)(b * S_ + t0 + row) * NQKV + 2048 + kvh * HD_ + d8]);
            *reinterpret_cast<bf16x8*>(&Ks[row][d8]) = kv;
        }
        // ---- stage V^T tile (128 dims x 64 keys), conflict-free b128 ----
        #pragma unroll
        for (int i = 0; i < 4; i++) {
            int f   = t + i * 256;
            int dim = f >> 3;
            int kc  = f & 7;
            bf16x8 vv = *reinterpret_cast<const bf16x8*>(
                &vbase[(size_t)dim * S_ + t0 + kc * 8]);
            *reinterpret_cast<bf16x8*>(&Vt[dim][kc * 8]) = vv;
        }
        __syncthreads();

        const int kofs = t0 - r0;   // >= 0 only on the last two tiles
        #pragma unroll
        for (int mt = 0; mt < 2; mt++) {
            // ---- S = Q K^T (16 q-rows x 64 keys) ----
            f32x4 s[4];
            #pragma unroll
            for (int n = 0; n < 4; n++) {
                f32x4 acc = (f32x4){0.f, 0.f, 0.f, 0.f};
                #pragma unroll
                for (int k = 0; k < 4; k++) {
                    bf16x8 bf = *reinterpret_cast<const bf16x8*>(
                        &Ks[n * 16 + col][k * 32 + quad * 8]);
                    acc = __builtin_amdgcn_mfma_f32_16x16x32_bf16(qf[mt][k], bf, acc, 0, 0, 0);
                }
                s[n] = acc;
            }

            // ---- online softmax ----
            float p[4][4];
            float alpha[4];
            #pragma unroll
            for (int r = 0; r < 4; r++) {
                float v0 = s[0][r] * SCALE, v1 = s[1][r] * SCALE;
                float v2 = s[2][r] * SCALE, v3 = s[3][r] * SCALE;
                if (kofs >= 0) {
                    int qloc = w * 32 + mt * 16 + quad * 4 + r;
                    if (kofs + 0 * 16 + col > qloc) v0 = -INFINITY;
                    if (kofs + 1 * 16 + col > qloc) v1 = -INFINITY;
                    if (kofs + 2 * 16 + col > qloc) v2 = -INFINITY;
                    if (kofs + 3 * 16 + col > qloc) v3 = -INFINITY;
                }
                float mx = fmaxf(fmaxf(v0, v1), fmaxf(v2, v3));
                #pragma unroll
                for (int off = 8; off; off >>= 1) mx = fmaxf(mx, __shfl_xor(mx, off));
                float mn = fmaxf(m_r[mt][r], mx);
                float al = __expf(m_r[mt][r] - mn);
                float p0 = __expf(v0 - mn);
                float p1 = __expf(v1 - mn);
                float p2 = __expf(v2 - mn);
                float p3 = __expf(v3 - mn);
                float ts = p0 + p1 + p2 + p3;
                #pragma unroll
                for (int off = 8; off; off >>= 1) ts += __shfl_xor(ts, off);
                l_r[mt][r] = l_r[mt][r] * al + ts;
                m_r[mt][r] = mn;
                alpha[r] = al;
                p[0][r] = p0; p[1][r] = p1; p[2][r] = p2; p[3][r] = p3;
            }

            #pragma unroll
            for (int n = 0; n < 4; n++)
                #pragma unroll
                for (int r = 0; r < 4; r++)
                    Ps[w][mt * 16 + quad * 4 + r][n * 16 + col] = (__bf16)p[n][r];

            #pragma unroll
            for (int n = 0; n < 8; n++)
                #pragma unroll
                for (int r = 0; r < 4; r++)
                    o_acc[mt][n][r] *= alpha[r];

            // ---- PV (same-wave RAW on Ps: no barrier needed) ----
            bf16x8 pf[2];
            #pragma unroll
            for (int ks = 0; ks < 2; ks++)
                pf[ks] = *reinterpret_cast<const bf16x8*>(
                    &Ps[w][mt * 16 + col][ks * 32 + quad * 8]);
            #pragma unroll
            for (int n = 0; n < 8; n++) {
                #pragma unroll
                for (int ks = 0; ks < 2; ks++) {
                    bf16x8 vf = *reinterpret_cast<const bf16x8*>(
                        &Vt[n * 16 + col][ks * 32 + quad * 8]);
                    o_acc[mt][n] = __builtin_amdgcn_mfma_f32_16x16x32_bf16(pf[ks], vf, o_acc[mt][n], 0, 0, 0);
                }
            }
        }
    }

    // ---- epilogue ----
    #pragma unroll
    for (int mt = 0; mt < 2; mt++) {
        #pragma unroll
        for (int r = 0; r < 4; r++) {
            float inv = 1.0f / l_r[mt][r];
            int qrow = r0 + w * 32 + mt * 16 + quad * 4 + r;
            __bf16* op = ao + (size_t)(b * S_ + qrow) * (H_ * HD_) + h * HD_ + col;
            #pragma unroll
            for (int n = 0; n < 8; n++)
                op[n * 16] = (__bf16)(o_acc[mt][n][r] * inv);
        }
    }
}

// ---------------------------------------------------------------------------
extern "C" void kernel_launch(void* const* d_in, const int* in_sizes, int n_in,
                              void* d_out, int out_size, void* d_ws, size_t ws_size,
                              hipStream_t stream) {
    const float* x  = (const float*)d_in[0];
    const float* wq = (const float*)d_in[1];
    const float* wk = (const float*)d_in[2];
    const float* wv = (const float*)d_in[3];
    const float* wo = (const float*)d_in[4];
    const float* qw = (const float*)d_in[5];
    const float* kw = (const float*)d_in[6];
    float* out = (float*)d_out;

    // workspace (bf16 elements), total 50.33M elems = 100.66 MB (same as R1 peak)
    __bf16* ws  = (__bf16*)d_ws;
    __bf16* xb  = ws;                               // [4096][2048]  8.4M
    __bf16* wb  = xb  + (size_t)8388608;            // [4096][2048]  8.4M (wq|wk|wv)
    __bf16* wob = wb  + (size_t)8388608;            // [2048][2048]  4.2M
    __bf16* qkv = wob + (size_t)4194304;            // [4096][4096] 16.8M
    __bf16* ao  = qkv + (size_t)16777216;           // [4096][2048]  8.4M
    __bf16* vtg = ao  + (size_t)8388608;            // [16][128][2048] 4.2M

    cvt_bf16<<<2097152 / 256, 256, 0, stream>>>(x,  xb,  2097152);
    cvt_bf16<<<1048576 / 256, 256, 0, stream>>>(wq, wb,  1048576);
    cvt_bf16<<< 524288 / 256, 256, 0, stream>>>(wk, wb + (size_t)2048 * 2048, 524288);
    cvt_bf16<<< 524288 / 256, 256, 0, stream>>>(wv, wb + (size_t)3072 * 2048, 524288);
    cvt_bf16<<<1048576 / 256, 256, 0, stream>>>(wo, wob, 1048576);

    // fused QKV projection
    gemm_bf16_nt<__bf16><<<dim3(NQKV / 128, BS_ / 128), 256, 0, stream>>>(
        xb, wb, qkv, BS_, NQKV, D_);

    // RMSNorm + RoPE on q and k
    norm_rope<<<dim3(BS_, H_),  128, 0, stream>>>(qkv,        qw);
    norm_rope<<<dim3(BS_, HK_), 128, 0, stream>>>(qkv + 2048, kw);

    // global V^T
    transpose_v<<<dim3(S_ / 64, B_ * HK_), 256, 0, stream>>>(qkv, vtg);

    // causal GQA attention
    attn_mfma<<<dim3(S_ / 128, B_ * H_), 256, 0, stream>>>(qkv, vtg, ao);

    // output projection
    gemm_bf16_nt<float><<<dim3(D_ / 128, BS_ / 128), 256, 0, stream>>>(
        ao, wob, out, BS_, D_, H_ * HD_);
}